// Round 1
// baseline (6549.448 us; speedup 1.0000x reference)
//
#include <hip/hip_runtime.h>

// TAGConv x2 on MI355X — round 0: correct f32 baseline.
// Pipeline: deg(segsum) -> rsqrt -> norm -> [gemm W[0]; 5x (scatter-add hop + gemm W[k])] x 2 layers.

namespace {
constexpr int NN = 100000;   // nodes
constexpr int NE = 1600000;  // edges
constexpr int KH = 5;        // hops

__global__ void deg_kernel(const int* __restrict__ col, const float* __restrict__ w,
                           float* __restrict__ deg) {
  int e = blockIdx.x * 256 + threadIdx.x;
  if (e < NE) atomicAdd(&deg[col[e]], w[e]);
}

__global__ void rsqrt_kernel(float* __restrict__ deg) {
  int n = blockIdx.x * 256 + threadIdx.x;
  if (n < NN) {
    float d = deg[n];
    deg[n] = d > 0.f ? rsqrtf(d) : 0.f;
  }
}

__global__ void norm_kernel(const int* __restrict__ row, const int* __restrict__ col,
                            const float* __restrict__ w, const float* __restrict__ dis,
                            float* __restrict__ norm) {
  int e = blockIdx.x * 256 + threadIdx.x;
  if (e < NE) norm[e] = dis[row[e]] * w[e] * dis[col[e]];
}

// h_next[col[e]*F + f] += h[row[e]*F + f] * norm[e], one thread per (e,f)
template <int LOG2F>
__global__ void scatter_kernel(const float* __restrict__ h, const float* __restrict__ norm,
                               const int* __restrict__ row, const int* __restrict__ col,
                               float* __restrict__ out) {
  constexpr unsigned F = 1u << LOG2F;
  unsigned idx = blockIdx.x * 256u + threadIdx.x;
  if (idx >= (unsigned)NE * F) return;
  unsigned e = idx >> LOG2F;
  unsigned f = idx & (F - 1u);
  float v = h[(unsigned)row[e] * F + f] * norm[e];
  atomicAdd(&out[(unsigned)col[e] * F + f], v);
}

// acc[n][j] (=|+=) sum_f h[n][f] * W[f][j]; 256 threads, NPB nodes per block.
template <int FI, int FO, bool ZERO>
__global__ void gemm_kernel(const float* __restrict__ h, const float* __restrict__ W,
                            float* __restrict__ acc) {
  constexpr int NPB = 256 / FO;
  __shared__ float sh[NPB * FI];
  unsigned n0 = blockIdx.x * NPB;
  for (int i = threadIdx.x; i < NPB * FI; i += 256) {
    unsigned nn = n0 + (unsigned)(i / FI);
    sh[i] = (nn < NN) ? h[nn * FI + (unsigned)(i % FI)] : 0.f;
  }
  __syncthreads();
  unsigned ln = threadIdx.x / FO;
  unsigned j = threadIdx.x % FO;
  unsigned n = n0 + ln;
  if (n >= NN) return;
  float a = 0.f;
#pragma unroll
  for (int f = 0; f < FI; ++f) a = fmaf(sh[ln * FI + f], W[f * FO + j], a);
  unsigned o = n * FO + j;
  if (ZERO) acc[o] = a; else acc[o] += a;
}

template <int F>
__global__ void bias_act_kernel(const float* __restrict__ acc, const float* __restrict__ b,
                                float* __restrict__ out) {
  unsigned idx = blockIdx.x * 256u + threadIdx.x;
  if (idx >= (unsigned)NN * F) return;
  float v = acc[idx] + b[idx & (F - 1u)];
  out[idx] = v >= 0.f ? v : 0.01f * v;
}

}  // namespace

extern "C" void kernel_launch(void* const* d_in, const int* in_sizes, int n_in,
                              void* d_out, int out_size, void* d_ws, size_t ws_size,
                              hipStream_t stream) {
  const float* x  = (const float*)d_in[0];
  const int*   ei = (const int*)d_in[1];   // [2, NE]: row then col
  const float* ew = (const float*)d_in[2];
  const float* W0 = (const float*)d_in[3]; // [6, 64, 128]
  const float* b0 = (const float*)d_in[4];
  const float* W1 = (const float*)d_in[5]; // [6, 128, 64]
  const float* b1 = (const float*)d_in[6];
  float* out = (float*)d_out;
  const int* row = ei;
  const int* col = ei + NE;

  // ws layout (floats): dis[100352] | norm[1600000] | acc[N*128] | bufA[N*128]
  constexpr size_t OFF_DIS  = 0;
  constexpr size_t OFF_NORM = 100352;
  constexpr size_t OFF_ACC  = OFF_NORM + 1600000;
  constexpr size_t OFF_BUFA = OFF_ACC + (size_t)NN * 128;
  constexpr size_t WS_FLOATS = OFF_BUFA + (size_t)NN * 128;
  if (ws_size < WS_FLOATS * sizeof(float)) return;  // workspace too small: fail visibly

  float* ws   = (float*)d_ws;
  float* dis  = ws + OFF_DIS;
  float* norm = ws + OFF_NORM;
  float* acc  = ws + OFF_ACC;
  float* bufA = ws + OFF_BUFA;
  float* t0   = bufA;                       // N*64
  float* t1   = bufA + (size_t)NN * 64;     // N*64

  const int TPB = 256;
  hipMemsetAsync(dis, 0, NN * sizeof(float), stream);
  deg_kernel<<<(NE + TPB - 1) / TPB, TPB, 0, stream>>>(col, ew, dis);
  rsqrt_kernel<<<(NN + TPB - 1) / TPB, TPB, 0, stream>>>(dis);
  norm_kernel<<<(NE + TPB - 1) / TPB, TPB, 0, stream>>>(row, col, ew, dis, norm);

  // ---- layer 0: F_IN=64 -> F_HID=128 ----
  gemm_kernel<64, 128, true><<<NN / 2, TPB, 0, stream>>>(x, W0, acc);
  const float* src = x;
  for (int k = 1; k <= KH; ++k) {
    float* dst = (k & 1) ? t0 : t1;
    hipMemsetAsync(dst, 0, (size_t)NN * 64 * sizeof(float), stream);
    scatter_kernel<6><<<(NE * 64 + TPB - 1) / TPB, TPB, 0, stream>>>(src, norm, row, col, dst);
    gemm_kernel<64, 128, false><<<NN / 2, TPB, 0, stream>>>(dst, W0 + k * 64 * 128, acc);
    src = dst;
  }
  bias_act_kernel<128><<<((size_t)NN * 128 + TPB - 1) / TPB, TPB, 0, stream>>>(acc, b0, acc);

  // ---- layer 1: F_HID=128 -> F_OUT=64 (h1 lives in acc) ----
  gemm_kernel<128, 64, true><<<NN / 4, TPB, 0, stream>>>(acc, W1, out);
  src = acc;
  for (int k = 1; k <= KH; ++k) {
    float* dst = (k & 1) ? bufA : acc;  // acc reusable after hop-1 consumed h1
    hipMemsetAsync(dst, 0, (size_t)NN * 128 * sizeof(float), stream);
    scatter_kernel<7><<<(NE * 128 + TPB - 1) / TPB, TPB, 0, stream>>>(src, norm, row, col, dst);
    gemm_kernel<128, 64, false><<<NN / 4, TPB, 0, stream>>>(dst, W1 + k * 128 * 64, out);
    src = dst;
  }
  bias_act_kernel<64><<<((size_t)NN * 64 + TPB - 1) / TPB, TPB, 0, stream>>>(out, b1, out);
}

// Round 2
// 2265.506 us; speedup vs baseline: 2.8909x; 2.8909x over previous
//
#include <hip/hip_runtime.h>

// TAGConv x2 on MI355X — round 1: CSR gather-reduce hops (no atomics) + register-blocked GEMM.

namespace {
constexpr int NN = 100000;   // nodes
constexpr int NE = 1600000;  // edges
constexpr int KH = 5;        // hops
constexpr int TPB = 256;

// ---------- preprocessing ----------
__global__ void deg_kernel(const int* __restrict__ col, const float* __restrict__ w,
                           float* __restrict__ deg) {
  int e = blockIdx.x * TPB + threadIdx.x;
  if (e < NE) atomicAdd(&deg[col[e]], w[e]);
}

__global__ void rsqrt_kernel(float* __restrict__ deg) {
  int n = blockIdx.x * TPB + threadIdx.x;
  if (n < NN) {
    float d = deg[n];
    deg[n] = d > 0.f ? rsqrtf(d) : 0.f;
  }
}

__global__ void hist_kernel(const int* __restrict__ col, int* __restrict__ cnt) {
  int e = blockIdx.x * TPB + threadIdx.x;
  if (e < NE) atomicAdd(&cnt[col[e]], 1);
}

// block-level inclusive scan (1024 threads), emits exclusive per-element + block totals
__global__ void scan1_kernel(const int* __restrict__ cnt, int* __restrict__ excl,
                             int* __restrict__ btot) {
  __shared__ int sh[1024];
  int i = blockIdx.x * 1024 + threadIdx.x;
  int v = (i < NN) ? cnt[i] : 0;
  sh[threadIdx.x] = v;
  __syncthreads();
  for (int ofs = 1; ofs < 1024; ofs <<= 1) {
    int t = (threadIdx.x >= ofs) ? sh[threadIdx.x - ofs] : 0;
    __syncthreads();
    sh[threadIdx.x] += t;
    __syncthreads();
  }
  if (i < NN) excl[i] = sh[threadIdx.x] - v;
  if (threadIdx.x == 1023) btot[blockIdx.x] = sh[1023];
}

// exclusive scan of the (<=128) block totals, single block
__global__ void scan2_kernel(int* __restrict__ btot, int nb) {
  __shared__ int sh[128];
  int t = threadIdx.x;
  if (t < nb) sh[t] = btot[t];
  __syncthreads();
  if (t == 0) {
    int run = 0;
    for (int b = 0; b < nb; ++b) { int x = sh[b]; sh[b] = run; run += x; }
  }
  __syncthreads();
  if (t < nb) btot[t] = sh[t];
}

__global__ void scan3_kernel(const int* __restrict__ excl, const int* __restrict__ btot,
                             int* __restrict__ rowptr, int* __restrict__ cursor) {
  int i = blockIdx.x * TPB + threadIdx.x;
  if (i < NN) {
    int v = excl[i] + btot[i >> 10];
    rowptr[i] = v;
    cursor[i] = v;
  }
  if (i == NN) rowptr[NN] = NE;
}

// permute (row, norm) into destination-sorted order; norm computed inline
__global__ void fill_kernel(const int* __restrict__ row, const int* __restrict__ col,
                            const float* __restrict__ w, const float* __restrict__ dis,
                            int* __restrict__ cursor, int2* __restrict__ edges) {
  int e = blockIdx.x * TPB + threadIdx.x;
  if (e >= NE) return;
  int r = row[e], c = col[e];
  float nw = dis[r] * w[e] * dis[c];
  int pos = atomicAdd(&cursor[c], 1);
  edges[pos] = make_int2(r, __float_as_int(nw));
}

// ---------- propagation: gather-reduce, F consecutive lanes per node ----------
template <int LOG2F>
__global__ void gather_hop(const float* __restrict__ h, const int2* __restrict__ edges,
                           const int* __restrict__ rowptr, float* __restrict__ out) {
  constexpr int F = 1 << LOG2F;
  constexpr int NPB = TPB / F;
  unsigned n = blockIdx.x * NPB + (threadIdx.x >> LOG2F);
  unsigned f = threadIdx.x & (F - 1u);
  if (n >= NN) return;
  int e = rowptr[n], e1 = rowptr[n + 1];
  float acc = 0.f;
  for (; e + 1 < e1; e += 2) {
    int2 ed0 = edges[e], ed1 = edges[e + 1];
    float v0 = h[(unsigned)ed0.x * F + f];
    float v1 = h[(unsigned)ed1.x * F + f];
    acc = fmaf(v0, __int_as_float(ed0.y), acc);
    acc = fmaf(v1, __int_as_float(ed1.y), acc);
  }
  if (e < e1) {
    int2 ed = edges[e];
    acc = fmaf(h[(unsigned)ed.x * F + f], __int_as_float(ed.y), acc);
  }
  out[n * F + f] = acc;
}

// ---------- dense: acc[n][j] (=|+=) sum_f h[n][f]*W[f][j], 8 nodes/thread ----------
template <int FI, int FO, bool ZERO>
__global__ void gemm2_kernel(const float* __restrict__ h, const float* __restrict__ W,
                             float* __restrict__ acc) {
  constexpr int NG = TPB / FO;       // node groups per block
  constexpr int NT = 8;              // nodes per thread
  constexpr int NPB = NG * NT;       // nodes per block (16 or 32; divides 100000)
  constexpr int PITCH = NPB + 2;     // float2-aligned, stride gcd(PITCH,32)=2 on stores
  __shared__ float xs[FI * PITCH];
  unsigned n0 = blockIdx.x * NPB;
  for (int i = threadIdx.x; i < NPB * FI; i += TPB) {
    int nn = i / FI, f = i % FI;
    xs[f * PITCH + nn] = h[(n0 + nn) * (unsigned)FI + f];
  }
  __syncthreads();
  int j = threadIdx.x % FO;
  int g = threadIdx.x / FO;
  float a[NT] = {0.f, 0.f, 0.f, 0.f, 0.f, 0.f, 0.f, 0.f};
  const float* wp = W + j;
  const float2* xbase = (const float2*)(xs + g * NT);
#pragma unroll 4
  for (int f = 0; f < FI; ++f) {
    float wv = wp[f * FO];
    const float2* xv = (const float2*)(xs + f * PITCH + g * NT);
    float2 x0 = xv[0], x1 = xv[1], x2 = xv[2], x3 = xv[3];
    a[0] = fmaf(x0.x, wv, a[0]); a[1] = fmaf(x0.y, wv, a[1]);
    a[2] = fmaf(x1.x, wv, a[2]); a[3] = fmaf(x1.y, wv, a[3]);
    a[4] = fmaf(x2.x, wv, a[4]); a[5] = fmaf(x2.y, wv, a[5]);
    a[6] = fmaf(x3.x, wv, a[6]); a[7] = fmaf(x3.y, wv, a[7]);
  }
  (void)xbase;
#pragma unroll
  for (int i = 0; i < NT; ++i) {
    unsigned o = (n0 + (unsigned)g * NT + i) * (unsigned)FO + j;
    if (ZERO) acc[o] = a[i]; else acc[o] += a[i];
  }
}

template <int F>
__global__ void bias_act_kernel(const float* __restrict__ acc, const float* __restrict__ b,
                                float* __restrict__ out) {
  unsigned idx = blockIdx.x * (unsigned)TPB + threadIdx.x;
  if (idx >= (unsigned)NN * F) return;
  float v = acc[idx] + b[idx & (F - 1u)];
  out[idx] = v >= 0.f ? v : 0.01f * v;
}

// ---------- round-0 fallback (atomic scatter) ----------
__global__ void norm_kernel(const int* __restrict__ row, const int* __restrict__ col,
                            const float* __restrict__ w, const float* __restrict__ dis,
                            float* __restrict__ norm) {
  int e = blockIdx.x * TPB + threadIdx.x;
  if (e < NE) norm[e] = dis[row[e]] * w[e] * dis[col[e]];
}

template <int LOG2F>
__global__ void scatter_kernel(const float* __restrict__ h, const float* __restrict__ norm,
                               const int* __restrict__ row, const int* __restrict__ col,
                               float* __restrict__ out) {
  constexpr unsigned F = 1u << LOG2F;
  unsigned idx = blockIdx.x * (unsigned)TPB + threadIdx.x;
  if (idx >= (unsigned)NE * F) return;
  unsigned e = idx >> LOG2F;
  unsigned f = idx & (F - 1u);
  float v = h[(unsigned)row[e] * F + f] * norm[e];
  atomicAdd(&out[(unsigned)col[e] * F + f], v);
}

}  // namespace

extern "C" void kernel_launch(void* const* d_in, const int* in_sizes, int n_in,
                              void* d_out, int out_size, void* d_ws, size_t ws_size,
                              hipStream_t stream) {
  const float* x  = (const float*)d_in[0];
  const int*   ei = (const int*)d_in[1];
  const float* ew = (const float*)d_in[2];
  const float* W0 = (const float*)d_in[3];
  const float* b0 = (const float*)d_in[4];
  const float* W1 = (const float*)d_in[5];
  const float* b1 = (const float*)d_in[6];
  float* out = (float*)d_out;
  const int* row = ei;
  const int* col = ei + NE;

  // CSR layout (4B words): dis[100352] | rowptr[100352] | btot[128] | edges int2[NE] | acc | bufA
  constexpr size_t OFF_DIS    = 0;
  constexpr size_t OFF_ROWPTR = 100352;
  constexpr size_t OFF_BTOT   = OFF_ROWPTR + 100352;
  constexpr size_t OFF_EDGES  = OFF_BTOT + 128;
  constexpr size_t OFF_ACC    = OFF_EDGES + 2 * (size_t)NE;
  constexpr size_t OFF_BUFA   = OFF_ACC + (size_t)NN * 128;
  constexpr size_t WS2_WORDS  = OFF_BUFA + (size_t)NN * 128;

  float* ws = (float*)d_ws;

  if (ws_size >= WS2_WORDS * sizeof(float)) {
    // ---------------- CSR gather path ----------------
    float* dis    = ws + OFF_DIS;
    int*   rowptr = (int*)(ws + OFF_ROWPTR);
    int*   btot   = (int*)(ws + OFF_BTOT);
    int2*  edges  = (int2*)(ws + OFF_EDGES);
    float* acc    = ws + OFF_ACC;
    float* bufA   = ws + OFF_BUFA;
    // transients overlapped into acc region (dead before first gemm writes acc)
    int* cnt    = (int*)acc;
    int* excl   = cnt + 100352;
    int* cursor = excl + 100352;

    hipMemsetAsync(dis, 0, NN * sizeof(float), stream);
    hipMemsetAsync(cnt, 0, NN * sizeof(int), stream);
    deg_kernel<<<(NE + TPB - 1) / TPB, TPB, 0, stream>>>(col, ew, dis);
    rsqrt_kernel<<<(NN + TPB - 1) / TPB, TPB, 0, stream>>>(dis);
    hist_kernel<<<(NE + TPB - 1) / TPB, TPB, 0, stream>>>(col, cnt);
    scan1_kernel<<<98, 1024, 0, stream>>>(cnt, excl, btot);
    scan2_kernel<<<1, 128, 0, stream>>>(btot, 98);
    scan3_kernel<<<(NN + TPB) / TPB, TPB, 0, stream>>>(excl, btot, rowptr, cursor);
    fill_kernel<<<(NE + TPB - 1) / TPB, TPB, 0, stream>>>(row, col, ew, dis, cursor, edges);

    float* t0 = bufA;
    float* t1 = bufA + (size_t)NN * 64;

    // layer 0: 64 -> 128
    gemm2_kernel<64, 128, true><<<NN / 16, TPB, 0, stream>>>(x, W0, acc);
    const float* src = x;
    for (int k = 1; k <= KH; ++k) {
      float* dst = (k & 1) ? t0 : t1;
      gather_hop<6><<<NN / 4 + 1, TPB, 0, stream>>>(src, edges, rowptr, dst);
      gemm2_kernel<64, 128, false><<<NN / 16, TPB, 0, stream>>>(dst, W0 + k * 64 * 128, acc);
      src = dst;
    }
    bias_act_kernel<128><<<(NN * 128 + TPB - 1) / TPB, TPB, 0, stream>>>(acc, b0, acc);

    // layer 1: 128 -> 64 (h1 in acc)
    gemm2_kernel<128, 64, true><<<NN / 32, TPB, 0, stream>>>(acc, W1, out);
    src = acc;
    for (int k = 1; k <= KH; ++k) {
      float* dst = (k & 1) ? bufA : acc;
      gather_hop<7><<<NN / 2 + 1, TPB, 0, stream>>>(src, edges, rowptr, dst);
      gemm2_kernel<128, 64, false><<<NN / 32, TPB, 0, stream>>>(dst, W1 + k * 128 * 64, out);
      src = dst;
    }
    bias_act_kernel<64><<<(NN * 64 + TPB - 1) / TPB, TPB, 0, stream>>>(out, b1, out);
    return;
  }

  // ---------------- fallback: round-0 atomic scatter path ----------------
  constexpr size_t F_OFF_DIS  = 0;
  constexpr size_t F_OFF_NORM = 100352;
  constexpr size_t F_OFF_ACC  = F_OFF_NORM + (size_t)NE;
  constexpr size_t F_OFF_BUFA = F_OFF_ACC + (size_t)NN * 128;
  float* dis  = ws + F_OFF_DIS;
  float* norm = ws + F_OFF_NORM;
  float* acc  = ws + F_OFF_ACC;
  float* bufA = ws + F_OFF_BUFA;
  float* t0 = bufA;
  float* t1 = bufA + (size_t)NN * 64;

  hipMemsetAsync(dis, 0, NN * sizeof(float), stream);
  deg_kernel<<<(NE + TPB - 1) / TPB, TPB, 0, stream>>>(col, ew, dis);
  rsqrt_kernel<<<(NN + TPB - 1) / TPB, TPB, 0, stream>>>(dis);
  norm_kernel<<<(NE + TPB - 1) / TPB, TPB, 0, stream>>>(row, col, ew, dis, norm);

  gemm2_kernel<64, 128, true><<<NN / 16, TPB, 0, stream>>>(x, W0, acc);
  const float* src = x;
  for (int k = 1; k <= KH; ++k) {
    float* dst = (k & 1) ? t0 : t1;
    hipMemsetAsync(dst, 0, (size_t)NN * 64 * sizeof(float), stream);
    scatter_kernel<6><<<(NE * 64 + TPB - 1) / TPB, TPB, 0, stream>>>(src, norm, row, col, dst);
    gemm2_kernel<64, 128, false><<<NN / 16, TPB, 0, stream>>>(dst, W0 + k * 64 * 128, acc);
    src = dst;
  }
  bias_act_kernel<128><<<(NN * 128 + TPB - 1) / TPB, TPB, 0, stream>>>(acc, b0, acc);

  gemm2_kernel<128, 64, true><<<NN / 32, TPB, 0, stream>>>(acc, W1, out);
  src = acc;
  for (int k = 1; k <= KH; ++k) {
    float* dst = (k & 1) ? bufA : acc;
    hipMemsetAsync(dst, 0, (size_t)NN * 128 * sizeof(float), stream);
    scatter_kernel<7><<<(NE * 128 + TPB - 1) / TPB, TPB, 0, stream>>>(src, norm, row, col, dst);
    gemm2_kernel<128, 64, false><<<NN / 32, TPB, 0, stream>>>(dst, W1 + k * 128 * 64, out);
    src = dst;
  }
  bias_act_kernel<64><<<(NN * 64 + TPB - 1) / TPB, TPB, 0, stream>>>(out, b1, out);
}

// Round 3
// 1328.871 us; speedup vs baseline: 4.9286x; 1.7048x over previous
//
#include <hip/hip_runtime.h>

// TAGConv x2 on MI355X — round 2: bf16 intermediates, Horner layer-1 (F=64 hops only),
// fused K=384 layer-0 GEMM. All accumulation f32; storage bf16.

namespace {
constexpr int NN = 100000;
constexpr int NE = 1600000;
constexpr int TPB = 256;

__device__ __forceinline__ float bflo(unsigned p) { return __uint_as_float(p << 16); }
__device__ __forceinline__ float bfhi(unsigned p) { return __uint_as_float(p & 0xffff0000u); }
__device__ __forceinline__ unsigned f2bf(float x) {
  unsigned u = __float_as_uint(x);
  return (u + 0x7fffu + ((u >> 16) & 1u)) >> 16;  // RNE
}
__device__ __forceinline__ unsigned pack2(float lo, float hi) {
  return f2bf(lo) | (f2bf(hi) << 16);
}
__device__ __forceinline__ float bf2f(unsigned short s) {
  return __uint_as_float(((unsigned)s) << 16);
}

// ---------- preprocessing ----------
__global__ void deg_kernel(const int* __restrict__ col, const float* __restrict__ w,
                           float* __restrict__ deg) {
  int e = blockIdx.x * TPB + threadIdx.x;
  if (e < NE) atomicAdd(&deg[col[e]], w[e]);
}

__global__ void rsqrt_kernel(float* __restrict__ deg) {
  int n = blockIdx.x * TPB + threadIdx.x;
  if (n < NN) {
    float d = deg[n];
    deg[n] = d > 0.f ? rsqrtf(d) : 0.f;
  }
}

__global__ void hist_kernel(const int* __restrict__ col, int* __restrict__ cnt) {
  int e = blockIdx.x * TPB + threadIdx.x;
  if (e < NE) atomicAdd(&cnt[col[e]], 1);
}

__global__ void scan1_kernel(const int* __restrict__ cnt, int* __restrict__ excl,
                             int* __restrict__ btot) {
  __shared__ int sh[1024];
  int i = blockIdx.x * 1024 + threadIdx.x;
  int v = (i < NN) ? cnt[i] : 0;
  sh[threadIdx.x] = v;
  __syncthreads();
  for (int ofs = 1; ofs < 1024; ofs <<= 1) {
    int t = (threadIdx.x >= ofs) ? sh[threadIdx.x - ofs] : 0;
    __syncthreads();
    sh[threadIdx.x] += t;
    __syncthreads();
  }
  if (i < NN) excl[i] = sh[threadIdx.x] - v;
  if (threadIdx.x == 1023) btot[blockIdx.x] = sh[1023];
}

__global__ void scan2_kernel(int* __restrict__ btot, int nb) {
  __shared__ int sh[128];
  int t = threadIdx.x;
  if (t < nb) sh[t] = btot[t];
  __syncthreads();
  if (t == 0) {
    int run = 0;
    for (int b = 0; b < nb; ++b) { int x = sh[b]; sh[b] = run; run += x; }
  }
  __syncthreads();
  if (t < nb) btot[t] = sh[t];
}

__global__ void scan3_kernel(const int* __restrict__ excl, const int* __restrict__ btot,
                             int* __restrict__ rowptr, int* __restrict__ cursor) {
  int i = blockIdx.x * TPB + threadIdx.x;
  if (i < NN) {
    int v = excl[i] + btot[i >> 10];
    rowptr[i] = v;
    cursor[i] = v;
  }
  if (i == NN) rowptr[NN] = NE;
}

__global__ void fill_kernel(const int* __restrict__ row, const int* __restrict__ col,
                            const float* __restrict__ w, const float* __restrict__ dis,
                            int* __restrict__ cursor, int2* __restrict__ edges) {
  int e = blockIdx.x * TPB + threadIdx.x;
  if (e >= NE) return;
  int r = row[e], c = col[e];
  float nw = dis[r] * w[e] * dis[c];
  int pos = atomicAdd(&cursor[c], 1);
  edges[pos] = make_int2(r, __float_as_int(nw));
}

// x f32 [N][64] -> Hcat slice 0 (bf16 [N][384], cols 0..63)
__global__ void convx_kernel(const float* __restrict__ x, unsigned* __restrict__ hcat) {
  unsigned idx = blockIdx.x * (unsigned)TPB + threadIdx.x;  // N*32
  if (idx >= (unsigned)NN * 32u) return;
  unsigned n = idx >> 5, p = idx & 31u;
  float2 v = *(const float2*)(x + (size_t)n * 64 + p * 2);
  hcat[(size_t)n * 192 + p] = pack2(v.x, v.y);
}

// ---------- hop: dst[n][f] = (YADD? y[n][f]:0) + sum_e norm*src[row][f], F=64 ----------
// 32 lanes per node, 2 bf16 feats per lane. src/dst strides in bf16 elements.
template <bool YADD, bool FINAL>
__global__ void hop_kernel(const unsigned short* __restrict__ src, int sstride,
                           const int2* __restrict__ edges, const int* __restrict__ rowptr,
                           const unsigned short* __restrict__ y,
                           unsigned short* __restrict__ dst, int dstride,
                           const float* __restrict__ bias, float* __restrict__ outf) {
  unsigned n = blockIdx.x * 8u + (threadIdx.x >> 5);
  unsigned lane = threadIdx.x & 31u;
  if (n >= NN) return;
  int e = rowptr[n], e1 = rowptr[n + 1];
  unsigned f0 = lane * 2u;
  float a0 = 0.f, a1 = 0.f;
  for (; e + 1 < e1; e += 2) {
    int2 d0 = edges[e], d1 = edges[e + 1];
    unsigned p0 = *(const unsigned*)(src + (size_t)(unsigned)d0.x * sstride + f0);
    unsigned p1 = *(const unsigned*)(src + (size_t)(unsigned)d1.x * sstride + f0);
    float w0 = __int_as_float(d0.y), w1 = __int_as_float(d1.y);
    a0 = fmaf(bflo(p0), w0, a0);
    a1 = fmaf(bfhi(p0), w0, a1);
    a0 = fmaf(bflo(p1), w1, a0);
    a1 = fmaf(bfhi(p1), w1, a1);
  }
  if (e < e1) {
    int2 d0 = edges[e];
    unsigned p0 = *(const unsigned*)(src + (size_t)(unsigned)d0.x * sstride + f0);
    float w0 = __int_as_float(d0.y);
    a0 = fmaf(bflo(p0), w0, a0);
    a1 = fmaf(bfhi(p0), w0, a1);
  }
  if (YADD) {
    unsigned yv = *(const unsigned*)(y + (size_t)n * 384 + f0);
    a0 += bflo(yv);
    a1 += bfhi(yv);
  }
  if (FINAL) {
    a0 += bias[f0]; a1 += bias[f0 + 1];
    a0 = a0 >= 0.f ? a0 : 0.01f * a0;
    a1 = a1 >= 0.f ? a1 : 0.01f * a1;
    *(float2*)(outf + (size_t)n * 64 + f0) = make_float2(a0, a1);
  } else {
    *(unsigned*)(dst + (size_t)n * dstride + f0) = pack2(a0, a1);
  }
}

// ---------- layer-0 fused GEMM: Hcat[N][384]bf16 @ W0[384][128]f32, bias+lrelu -> h1b bf16 ----------
__global__ void gemm_l0(const unsigned short* __restrict__ A, const float* __restrict__ W,
                        const float* __restrict__ bias, unsigned short* __restrict__ H1) {
  constexpr int KK = 384, FO = 128, NT = 8, NPB = 16, PITCH = NPB + 2;
  __shared__ float xs[KK * PITCH];  // 27.6 KB
  unsigned n0 = blockIdx.x * NPB;
  for (int i = threadIdx.x; i < NPB * KK; i += TPB) {
    int nn = i / KK, f = i - nn * KK;
    xs[f * PITCH + nn] = bf2f(A[(size_t)(n0 + nn) * KK + f]);
  }
  __syncthreads();
  int j = threadIdx.x & (FO - 1);
  int g = threadIdx.x >> 7;
  float a[NT] = {};
#pragma unroll 4
  for (int f = 0; f < KK; ++f) {
    float wv = W[f * FO + j];
    const float2* xv = (const float2*)(xs + f * PITCH + g * NT);
    float2 x0 = xv[0], x1 = xv[1], x2 = xv[2], x3 = xv[3];
    a[0] = fmaf(x0.x, wv, a[0]); a[1] = fmaf(x0.y, wv, a[1]);
    a[2] = fmaf(x1.x, wv, a[2]); a[3] = fmaf(x1.y, wv, a[3]);
    a[4] = fmaf(x2.x, wv, a[4]); a[5] = fmaf(x2.y, wv, a[5]);
    a[6] = fmaf(x3.x, wv, a[6]); a[7] = fmaf(x3.y, wv, a[7]);
  }
  float bv = bias[j];
#pragma unroll
  for (int i = 0; i < NT; ++i) {
    float v = a[i] + bv;
    v = v >= 0.f ? v : 0.01f * v;
    H1[(size_t)(n0 + (unsigned)g * NT + i) * FO + j] = (unsigned short)f2bf(v);
  }
}

// ---------- layer-1 GEMM: h1b[N][128]bf16 @ W1(indexed) -> Y[N][384] bf16, col tile = blockIdx.y ----------
__global__ void gemm_l1(const unsigned short* __restrict__ A, const float* __restrict__ W1,
                        unsigned short* __restrict__ Y) {
  constexpr int KK = 128, NT = 8, NPB = 16, PITCH = NPB + 2;
  __shared__ float xs[KK * PITCH];  // 9.2 KB
  unsigned n0 = blockIdx.x * NPB;
  int J = blockIdx.y * 128 + (threadIdx.x & 127);
  const float* Wb = W1 + (size_t)(J >> 6) * (128 * 64) + (J & 63);
  for (int i = threadIdx.x; i < NPB * KK; i += TPB) {
    int nn = i >> 7, f = i & 127;
    xs[f * PITCH + nn] = bf2f(A[(size_t)(n0 + nn) * KK + f]);
  }
  __syncthreads();
  int g = threadIdx.x >> 7;
  float a[NT] = {};
#pragma unroll 4
  for (int f = 0; f < KK; ++f) {
    float wv = Wb[f * 64];
    const float2* xv = (const float2*)(xs + f * PITCH + g * NT);
    float2 x0 = xv[0], x1 = xv[1], x2 = xv[2], x3 = xv[3];
    a[0] = fmaf(x0.x, wv, a[0]); a[1] = fmaf(x0.y, wv, a[1]);
    a[2] = fmaf(x1.x, wv, a[2]); a[3] = fmaf(x1.y, wv, a[3]);
    a[4] = fmaf(x2.x, wv, a[4]); a[5] = fmaf(x2.y, wv, a[5]);
    a[6] = fmaf(x3.x, wv, a[6]); a[7] = fmaf(x3.y, wv, a[7]);
  }
#pragma unroll
  for (int i = 0; i < NT; ++i)
    Y[(size_t)(n0 + (unsigned)g * NT + i) * 384 + J] = (unsigned short)f2bf(a[i]);
}

}  // namespace

extern "C" void kernel_launch(void* const* d_in, const int* in_sizes, int n_in,
                              void* d_out, int out_size, void* d_ws, size_t ws_size,
                              hipStream_t stream) {
  const float* x  = (const float*)d_in[0];
  const int*   ei = (const int*)d_in[1];
  const float* ew = (const float*)d_in[2];
  const float* W0 = (const float*)d_in[3];  // [6][64][128] == [384][128]
  const float* b0 = (const float*)d_in[4];
  const float* W1 = (const float*)d_in[5];  // [6][128][64]
  const float* b1 = (const float*)d_in[6];
  float* out = (float*)d_out;
  const int* row = ei;
  const int* col = ei + NE;

  // ws layout (4B words):
  // dis[100352] | rowptr[100352] | btot[128] | edges int2[NE] | Hcat bf16[N][384] | H1 bf16[N][128]
  constexpr size_t OFF_DIS    = 0;
  constexpr size_t OFF_ROWPTR = 100352;
  constexpr size_t OFF_BTOT   = OFF_ROWPTR + 100352;
  constexpr size_t OFF_EDGES  = OFF_BTOT + 128;
  constexpr size_t OFF_HCAT   = OFF_EDGES + 2 * (size_t)NE;          // 19.2M words
  constexpr size_t OFF_H1     = OFF_HCAT + (size_t)NN * 384 / 2;     // 6.4M words
  constexpr size_t WS_WORDS   = OFF_H1 + (size_t)NN * 128 / 2;
  if (ws_size < WS_WORDS * sizeof(float)) return;  // proven sufficient in round 1

  float* ws = (float*)d_ws;
  float* dis    = ws + OFF_DIS;
  int*   rowptr = (int*)(ws + OFF_ROWPTR);
  int*   btot   = (int*)(ws + OFF_BTOT);
  int2*  edges  = (int2*)(ws + OFF_EDGES);
  unsigned short* Hcat = (unsigned short*)(ws + OFF_HCAT);  // [N][384]
  unsigned short* H1   = (unsigned short*)(ws + OFF_H1);    // [N][128]
  // preprocessing transients live in H1 region (dead until gemm_l0 writes it)
  int* cnt    = (int*)H1;
  int* excl   = cnt + 100352;
  int* cursor = excl + 100352;
  // layer-1 Horner z ping-pong overlays H1 region after gemm_l1 consumed it
  unsigned short* z0 = H1;                       // [N][64] bf16 = 1.6M words
  unsigned short* z1 = H1 + (size_t)NN * 64;

  hipMemsetAsync(dis, 0, NN * sizeof(float), stream);
  hipMemsetAsync(cnt, 0, NN * sizeof(int), stream);
  deg_kernel<<<(NE + TPB - 1) / TPB, TPB, 0, stream>>>(col, ew, dis);
  rsqrt_kernel<<<(NN + TPB - 1) / TPB, TPB, 0, stream>>>(dis);
  hist_kernel<<<(NE + TPB - 1) / TPB, TPB, 0, stream>>>(col, cnt);
  scan1_kernel<<<98, 1024, 0, stream>>>(cnt, excl, btot);
  scan2_kernel<<<1, 128, 0, stream>>>(btot, 98);
  scan3_kernel<<<(NN + TPB) / TPB, TPB, 0, stream>>>(excl, btot, rowptr, cursor);
  fill_kernel<<<(NE + TPB - 1) / TPB, TPB, 0, stream>>>(row, col, ew, dis, cursor, edges);

  // layer 0: h_k slices into Hcat, then one fused K=384 GEMM
  convx_kernel<<<NN * 32 / TPB, TPB, 0, stream>>>(x, (unsigned*)Hcat);
  for (int k = 1; k <= 5; ++k) {
    hop_kernel<false, false><<<NN / 8, TPB, 0, stream>>>(
        Hcat + (k - 1) * 64, 384, edges, rowptr, nullptr,
        Hcat + k * 64, 384, nullptr, nullptr);
  }
  gemm_l0<<<NN / 16, TPB, 0, stream>>>(Hcat, W0, b0, H1);

  // layer 1: Y = h1 @ [W1[0..5]] -> Horner hops at F=64
  gemm_l1<<<dim3(NN / 16, 3), TPB, 0, stream>>>(H1, W1, Hcat);  // Y overwrites Hcat
  const unsigned short* Y = Hcat;
  // z = y5; z = y4 + A z; ... ; out = lrelu(y0 + A z + b1)
  hop_kernel<true, false><<<NN / 8, TPB, 0, stream>>>(
      Y + 5 * 64, 384, edges, rowptr, Y + 4 * 64, z0, 64, nullptr, nullptr);
  hop_kernel<true, false><<<NN / 8, TPB, 0, stream>>>(
      z0, 64, edges, rowptr, Y + 3 * 64, z1, 64, nullptr, nullptr);
  hop_kernel<true, false><<<NN / 8, TPB, 0, stream>>>(
      z1, 64, edges, rowptr, Y + 2 * 64, z0, 64, nullptr, nullptr);
  hop_kernel<true, false><<<NN / 8, TPB, 0, stream>>>(
      z0, 64, edges, rowptr, Y + 1 * 64, z1, 64, nullptr, nullptr);
  hop_kernel<true, true><<<NN / 8, TPB, 0, stream>>>(
      z1, 64, edges, rowptr, Y + 0 * 64, nullptr, 0, b1, out);
}

// Round 4
// 865.973 us; speedup vs baseline: 7.5631x; 1.5345x over previous
//
#include <hip/hip_runtime.h>

// TAGConv x2 on MI355X — round 3: MFMA bf16 GEMMs (fragment-preordered W, no LDS),
// 4x-unrolled gather hops, fused deg+hist. Storage bf16, accumulation f32.

namespace {
constexpr int NN = 100000;
constexpr int NE = 1600000;
constexpr int TPB = 256;

typedef __attribute__((ext_vector_type(8))) short short8v;
typedef __attribute__((ext_vector_type(4))) float float4v;

__device__ __forceinline__ float bflo(unsigned p) { return __uint_as_float(p << 16); }
__device__ __forceinline__ float bfhi(unsigned p) { return __uint_as_float(p & 0xffff0000u); }
__device__ __forceinline__ unsigned f2bf(float x) {
  unsigned u = __float_as_uint(x);
  return (u + 0x7fffu + ((u >> 16) & 1u)) >> 16;  // RNE
}
__device__ __forceinline__ unsigned pack2(float lo, float hi) {
  return f2bf(lo) | (f2bf(hi) << 16);
}

// ---------- preprocessing ----------
__global__ void deg_hist_kernel(const int* __restrict__ col, const float* __restrict__ w,
                                float* __restrict__ deg, int* __restrict__ cnt) {
  int e = blockIdx.x * TPB + threadIdx.x;
  if (e < NE) {
    int c = col[e];
    atomicAdd(&deg[c], w[e]);
    atomicAdd(&cnt[c], 1);
  }
}

__global__ void rsqrt_kernel(float* __restrict__ deg) {
  int n = blockIdx.x * TPB + threadIdx.x;
  if (n < NN) {
    float d = deg[n];
    deg[n] = d > 0.f ? rsqrtf(d) : 0.f;
  }
}

__global__ void scan1_kernel(const int* __restrict__ cnt, int* __restrict__ excl,
                             int* __restrict__ btot) {
  __shared__ int sh[1024];
  int i = blockIdx.x * 1024 + threadIdx.x;
  int v = (i < NN) ? cnt[i] : 0;
  sh[threadIdx.x] = v;
  __syncthreads();
  for (int ofs = 1; ofs < 1024; ofs <<= 1) {
    int t = (threadIdx.x >= ofs) ? sh[threadIdx.x - ofs] : 0;
    __syncthreads();
    sh[threadIdx.x] += t;
    __syncthreads();
  }
  if (i < NN) excl[i] = sh[threadIdx.x] - v;
  if (threadIdx.x == 1023) btot[blockIdx.x] = sh[1023];
}

__global__ void scan2_kernel(int* __restrict__ btot, int nb) {
  __shared__ int sh[128];
  int t = threadIdx.x;
  if (t < nb) sh[t] = btot[t];
  __syncthreads();
  if (t == 0) {
    int run = 0;
    for (int b = 0; b < nb; ++b) { int x = sh[b]; sh[b] = run; run += x; }
  }
  __syncthreads();
  if (t < nb) btot[t] = sh[t];
}

__global__ void scan3_kernel(const int* __restrict__ excl, const int* __restrict__ btot,
                             int* __restrict__ rowptr, int* __restrict__ cursor) {
  int i = blockIdx.x * TPB + threadIdx.x;
  if (i < NN) {
    int v = excl[i] + btot[i >> 10];
    rowptr[i] = v;
    cursor[i] = v;
  }
  if (i == NN) rowptr[NN] = NE;
}

__global__ void fill_kernel(const int* __restrict__ row, const int* __restrict__ col,
                            const float* __restrict__ w, const float* __restrict__ dis,
                            int* __restrict__ cursor, int2* __restrict__ edges) {
  int e = blockIdx.x * TPB + threadIdx.x;
  if (e >= NE) return;
  int r = row[e], c = col[e];
  float nw = dis[r] * w[e] * dis[c];
  int pos = atomicAdd(&cursor[c], 1);
  edges[pos] = make_int2(r, __float_as_int(nw));
}

// W0 [384][128] f32 -> fragment-ordered bf16: idx ((s*8+nt)*64+l)*8+j = W0[s*32+(l>>4)*8+j][nt*16+(l&15)]
__global__ void wfrag0_kernel(const float* __restrict__ W0, short* __restrict__ F) {
  int t = blockIdx.x * TPB + threadIdx.x;
  if (t >= 12 * 8 * 64) return;
  int l = t & 63, nt = (t >> 6) & 7, s = t >> 9;
  int c = nt * 16 + (l & 15);
  int kb = s * 32 + (l >> 4) * 8;
  short8v v;
#pragma unroll
  for (int j = 0; j < 8; ++j) v[j] = (short)f2bf(W0[(kb + j) * 128 + c]);
  *(short8v*)(F + (size_t)t * 8) = v;
}

// W1 [6][128][64] viewed as B[f][J]=W1[J>>6][f][J&63], J in 0..383:
// idx ((s*24+nt)*64+l)*8+j = B[s*32+(l>>4)*8+j][nt*16+(l&15)]
__global__ void wfrag1_kernel(const float* __restrict__ W1, short* __restrict__ F) {
  int t = blockIdx.x * TPB + threadIdx.x;
  if (t >= 4 * 24 * 64) return;
  int l = t & 63, nt = (t >> 6) % 24, s = t / (64 * 24);
  int J = nt * 16 + (l & 15);
  int fb = s * 32 + (l >> 4) * 8;
  const float* Wb = W1 + (size_t)(J >> 6) * (128 * 64) + (J & 63);
  short8v v;
#pragma unroll
  for (int j = 0; j < 8; ++j) v[j] = (short)f2bf(Wb[(size_t)(fb + j) * 64]);
  *(short8v*)(F + (size_t)t * 8) = v;
}

// x f32 [N][64] -> Hcat slice 0 (bf16 [N][384], cols 0..63)
__global__ void convx_kernel(const float* __restrict__ x, unsigned* __restrict__ hcat) {
  unsigned idx = blockIdx.x * (unsigned)TPB + threadIdx.x;
  if (idx >= (unsigned)NN * 32u) return;
  unsigned n = idx >> 5, p = idx & 31u;
  float2 v = *(const float2*)(x + (size_t)n * 64 + p * 2);
  hcat[(size_t)n * 192 + p] = pack2(v.x, v.y);
}

// ---------- hop: dst[n][f] = (YADD? y[n][f]:0) + sum_e norm*src[row][f], F=64, 32 lanes/node ----------
template <bool YADD, bool FINAL>
__global__ void hop_kernel(const unsigned short* __restrict__ src, int sstride,
                           const int2* __restrict__ edges, const int* __restrict__ rowptr,
                           const unsigned short* __restrict__ y,
                           unsigned short* __restrict__ dst, int dstride,
                           const float* __restrict__ bias, float* __restrict__ outf) {
  unsigned n = blockIdx.x * 8u + (threadIdx.x >> 5);
  unsigned lane = threadIdx.x & 31u;
  if (n >= NN) return;
  int e = rowptr[n], e1 = rowptr[n + 1];
  unsigned f0 = lane * 2u;
  float a0 = 0.f, a1 = 0.f;
  for (; e + 3 < e1; e += 4) {
    int2 d0 = edges[e], d1 = edges[e + 1], d2 = edges[e + 2], d3 = edges[e + 3];
    unsigned p0 = *(const unsigned*)(src + (size_t)(unsigned)d0.x * sstride + f0);
    unsigned p1 = *(const unsigned*)(src + (size_t)(unsigned)d1.x * sstride + f0);
    unsigned p2 = *(const unsigned*)(src + (size_t)(unsigned)d2.x * sstride + f0);
    unsigned p3 = *(const unsigned*)(src + (size_t)(unsigned)d3.x * sstride + f0);
    float w0 = __int_as_float(d0.y), w1 = __int_as_float(d1.y);
    float w2 = __int_as_float(d2.y), w3 = __int_as_float(d3.y);
    a0 = fmaf(bflo(p0), w0, a0); a1 = fmaf(bfhi(p0), w0, a1);
    a0 = fmaf(bflo(p1), w1, a0); a1 = fmaf(bfhi(p1), w1, a1);
    a0 = fmaf(bflo(p2), w2, a0); a1 = fmaf(bfhi(p2), w2, a1);
    a0 = fmaf(bflo(p3), w3, a0); a1 = fmaf(bfhi(p3), w3, a1);
  }
  for (; e < e1; ++e) {
    int2 d0 = edges[e];
    unsigned p0 = *(const unsigned*)(src + (size_t)(unsigned)d0.x * sstride + f0);
    float w0 = __int_as_float(d0.y);
    a0 = fmaf(bflo(p0), w0, a0); a1 = fmaf(bfhi(p0), w0, a1);
  }
  if (YADD) {
    unsigned yv = *(const unsigned*)(y + (size_t)n * 384 + f0);
    a0 += bflo(yv);
    a1 += bfhi(yv);
  }
  if (FINAL) {
    a0 += bias[f0]; a1 += bias[f0 + 1];
    a0 = a0 >= 0.f ? a0 : 0.01f * a0;
    a1 = a1 >= 0.f ? a1 : 0.01f * a1;
    *(float2*)(outf + (size_t)n * 64 + f0) = make_float2(a0, a1);
  } else {
    *(unsigned*)(dst + (size_t)n * dstride + f0) = pack2(a0, a1);
  }
}

// ---------- MFMA GEMM layer 0: Hcat[N][384]bf16 @ W0frag -> bias+lrelu -> H1[N][128]bf16 ----------
// block = 256 thr = 4 waves, 64 rows/block; wave w: rows blockIdx*64 + w*16, all 8 col-tiles.
__global__ void gemm_l0(const unsigned short* __restrict__ A, const short* __restrict__ W0f,
                        const float* __restrict__ bias, unsigned short* __restrict__ H1) {
  int wave = threadIdx.x >> 6, lane = threadIdx.x & 63;
  int lrow = lane & 15, lk = lane >> 4;
  unsigned r0 = blockIdx.x * 64u + (unsigned)wave * 16u;
  unsigned arow = r0 + (unsigned)lrow;
  if (arow >= NN) arow = NN - 1;  // clamp (results discarded by store guard)
  const short8v* Ab = (const short8v*)(A + (size_t)arow * 384 + (unsigned)lk * 8);
  const short8v* Bb = (const short8v*)W0f + lane;
  float4v acc[8] = {};
#pragma unroll
  for (int s = 0; s < 12; ++s) {
    short8v a = Ab[s * 4];
#pragma unroll
    for (int nt = 0; nt < 8; ++nt) {
      short8v b = Bb[(s * 8 + nt) * 64];
      acc[nt] = __builtin_amdgcn_mfma_f32_16x16x32_bf16(a, b, acc[nt], 0, 0, 0);
    }
  }
#pragma unroll
  for (int nt = 0; nt < 8; ++nt) {
    int c = nt * 16 + lrow;
    float bv = bias[c];
#pragma unroll
    for (int r = 0; r < 4; ++r) {
      unsigned n = r0 + (unsigned)(lk * 4 + r);
      if (n < NN) {
        float v = acc[nt][r] + bv;
        v = v >= 0.f ? v : 0.01f * v;
        H1[(size_t)n * 128 + c] = (unsigned short)f2bf(v);
      }
    }
  }
}

// ---------- MFMA GEMM layer 1: H1[N][128]bf16 @ W1frag -> Y[N][384]bf16 ----------
__global__ void gemm_l1(const unsigned short* __restrict__ A, const short* __restrict__ W1f,
                        unsigned short* __restrict__ Y) {
  int wave = threadIdx.x >> 6, lane = threadIdx.x & 63;
  int lrow = lane & 15, lk = lane >> 4;
  unsigned r0 = blockIdx.x * 64u + (unsigned)wave * 16u;
  unsigned arow = r0 + (unsigned)lrow;
  if (arow >= NN) arow = NN - 1;
  const short8v* Ab = (const short8v*)(A + (size_t)arow * 128 + (unsigned)lk * 8);
  const short8v* Bb = (const short8v*)W1f + lane;
  float4v acc[24] = {};
#pragma unroll
  for (int s = 0; s < 4; ++s) {
    short8v a = Ab[s * 4];
#pragma unroll
    for (int nt = 0; nt < 24; ++nt) {
      short8v b = Bb[(s * 24 + nt) * 64];
      acc[nt] = __builtin_amdgcn_mfma_f32_16x16x32_bf16(a, b, acc[nt], 0, 0, 0);
    }
  }
#pragma unroll
  for (int nt = 0; nt < 24; ++nt) {
    int c = nt * 16 + lrow;
#pragma unroll
    for (int r = 0; r < 4; ++r) {
      unsigned n = r0 + (unsigned)(lk * 4 + r);
      if (n < NN) Y[(size_t)n * 384 + c] = (unsigned short)f2bf(acc[nt][r]);
    }
  }
}

}  // namespace

extern "C" void kernel_launch(void* const* d_in, const int* in_sizes, int n_in,
                              void* d_out, int out_size, void* d_ws, size_t ws_size,
                              hipStream_t stream) {
  const float* x  = (const float*)d_in[0];
  const int*   ei = (const int*)d_in[1];
  const float* ew = (const float*)d_in[2];
  const float* W0 = (const float*)d_in[3];  // [6][64][128] == [384][128]
  const float* b0 = (const float*)d_in[4];
  const float* W1 = (const float*)d_in[5];  // [6][128][64]
  const float* b1 = (const float*)d_in[6];
  float* out = (float*)d_out;
  const int* row = ei;
  const int* col = ei + NE;

  // ws (4B words): dis[100352] | rowptr[100352] | btot[128] | edges int2[NE] | Hcat bf16[N][384] | H1 bf16[N][128]
  constexpr size_t OFF_DIS    = 0;
  constexpr size_t OFF_ROWPTR = 100352;
  constexpr size_t OFF_BTOT   = OFF_ROWPTR + 100352;
  constexpr size_t OFF_EDGES  = OFF_BTOT + 128;
  constexpr size_t OFF_HCAT   = OFF_EDGES + 2 * (size_t)NE;
  constexpr size_t OFF_H1     = OFF_HCAT + (size_t)NN * 384 / 2;
  constexpr size_t WS_WORDS   = OFF_H1 + (size_t)NN * 128 / 2;
  if (ws_size < WS_WORDS * sizeof(float)) return;

  float* ws = (float*)d_ws;
  float* dis    = ws + OFF_DIS;
  int*   rowptr = (int*)(ws + OFF_ROWPTR);
  int*   btot   = (int*)(ws + OFF_BTOT);
  int2*  edges  = (int2*)(ws + OFF_EDGES);
  unsigned short* Hcat = (unsigned short*)(ws + OFF_HCAT);
  unsigned short* H1   = (unsigned short*)(ws + OFF_H1);
  // W fragments overlay the dis region (dead after fill_kernel): 24576 + 24576 words <= 100352
  short* W0f = (short*)(ws + OFF_DIS);
  short* W1f = (short*)(ws + OFF_DIS + 24576);
  // preprocessing transients in H1 region (dead until gemm_l0 writes it)
  int* cnt    = (int*)H1;
  int* excl   = cnt + 100352;
  int* cursor = excl + 100352;
  // layer-1 Horner ping-pong overlays H1 region after gemm_l1 consumed it
  unsigned short* z0 = H1;
  unsigned short* z1 = H1 + (size_t)NN * 64;

  hipMemsetAsync(dis, 0, NN * sizeof(float), stream);
  hipMemsetAsync(cnt, 0, NN * sizeof(int), stream);
  deg_hist_kernel<<<(NE + TPB - 1) / TPB, TPB, 0, stream>>>(col, ew, dis, cnt);
  rsqrt_kernel<<<(NN + TPB - 1) / TPB, TPB, 0, stream>>>(dis);
  scan1_kernel<<<98, 1024, 0, stream>>>(cnt, excl, btot);
  scan2_kernel<<<1, 128, 0, stream>>>(btot, 98);
  scan3_kernel<<<(NN + TPB) / TPB, TPB, 0, stream>>>(excl, btot, rowptr, cursor);
  fill_kernel<<<(NE + TPB - 1) / TPB, TPB, 0, stream>>>(row, col, ew, dis, cursor, edges);
  // dis dead -> build W fragments in its place
  wfrag0_kernel<<<24, TPB, 0, stream>>>(W0, W0f);
  wfrag1_kernel<<<24, TPB, 0, stream>>>(W1, W1f);

  // layer 0: slices into Hcat, then one MFMA GEMM (K=384)
  convx_kernel<<<NN * 32 / TPB, TPB, 0, stream>>>(x, (unsigned*)Hcat);
  for (int k = 1; k <= 5; ++k) {
    hop_kernel<false, false><<<NN / 8, TPB, 0, stream>>>(
        Hcat + (k - 1) * 64, 384, edges, rowptr, nullptr,
        Hcat + k * 64, 384, nullptr, nullptr);
  }
  gemm_l0<<<(NN + 63) / 64, TPB, 0, stream>>>(Hcat, W0f, b0, H1);

  // layer 1: Y = h1 @ [W1[0..5]] (overwrites Hcat), then Horner hops at F=64
  gemm_l1<<<(NN + 63) / 64, TPB, 0, stream>>>(H1, W1f, Hcat);
  const unsigned short* Y = Hcat;
  hop_kernel<true, false><<<NN / 8, TPB, 0, stream>>>(
      Y + 5 * 64, 384, edges, rowptr, Y + 4 * 64, z0, 64, nullptr, nullptr);
  hop_kernel<true, false><<<NN / 8, TPB, 0, stream>>>(
      z0, 64, edges, rowptr, Y + 3 * 64, z1, 64, nullptr, nullptr);
  hop_kernel<true, false><<<NN / 8, TPB, 0, stream>>>(
      z1, 64, edges, rowptr, Y + 2 * 64, z0, 64, nullptr, nullptr);
  hop_kernel<true, false><<<NN / 8, TPB, 0, stream>>>(
      z0, 64, edges, rowptr, Y + 1 * 64, z1, 64, nullptr, nullptr);
  hop_kernel<true, true><<<NN / 8, TPB, 0, stream>>>(
      z1, 64, edges, rowptr, Y + 0 * 64, nullptr, 0, b1, out);
}

// Round 5
// 656.820 us; speedup vs baseline: 9.9715x; 1.3184x over previous
//
#include <hip/hip_runtime.h>

// TAGConv x2 on MI355X — round 4: single-u64-atomic preprocessing (deg+hist+rank in one
// atomicAdd, atomic-free fill), 8-lane/node dwordx4 gather hops, MFMA bf16 GEMMs.

namespace {
constexpr int NN = 100000;
constexpr int NE = 1600000;
constexpr int TPB = 256;

typedef __attribute__((ext_vector_type(8))) short short8v;
typedef __attribute__((ext_vector_type(4))) float float4v;

__device__ __forceinline__ float bflo(unsigned p) { return __uint_as_float(p << 16); }
__device__ __forceinline__ float bfhi(unsigned p) { return __uint_as_float(p & 0xffff0000u); }
__device__ __forceinline__ unsigned f2bf(float x) {
  unsigned u = __float_as_uint(x);
  return (u + 0x7fffu + ((u >> 16) & 1u)) >> 16;  // RNE
}
__device__ __forceinline__ unsigned pack2(float lo, float hi) {
  return f2bf(lo) | (f2bf(hi) << 16);
}

// ---------- preprocessing ----------
// One u64 atomic per edge: acc64[c] += (1<<40) | fixed24(w). Returned old value gives
// this edge's rank (old>>40) and accumulates deg (low 40 bits, 2^-24 fixed point).
__global__ void pass1_kernel(const int* __restrict__ col, const float* __restrict__ w,
                             unsigned long long* __restrict__ acc64, int* __restrict__ rank) {
  int e = blockIdx.x * TPB + threadIdx.x;
  if (e >= NE) return;
  int c = col[e];
  unsigned long long v = (1ULL << 40) | (unsigned long long)__float2uint_rn(w[e] * 16777216.0f);
  unsigned long long old = atomicAdd(&acc64[c], v);
  rank[e] = (int)(old >> 40);
}

__global__ void dis_kernel(const unsigned long long* __restrict__ acc64,
                           float* __restrict__ dis) {
  int n = blockIdx.x * TPB + threadIdx.x;
  if (n >= NN) return;
  unsigned long long u = acc64[n] & ((1ULL << 40) - 1);
  float d = (float)u * (1.0f / 16777216.0f);
  dis[n] = d > 0.f ? rsqrtf(d) : 0.f;
}

__global__ void scan1_kernel(const unsigned long long* __restrict__ acc64,
                             int* __restrict__ excl, int* __restrict__ btot) {
  __shared__ int sh[1024];
  int i = blockIdx.x * 1024 + threadIdx.x;
  int v = (i < NN) ? (int)(acc64[i] >> 40) : 0;
  sh[threadIdx.x] = v;
  __syncthreads();
  for (int ofs = 1; ofs < 1024; ofs <<= 1) {
    int t = (threadIdx.x >= ofs) ? sh[threadIdx.x - ofs] : 0;
    __syncthreads();
    sh[threadIdx.x] += t;
    __syncthreads();
  }
  if (i < NN) excl[i] = sh[threadIdx.x] - v;
  if (threadIdx.x == 1023) btot[blockIdx.x] = sh[1023];
}

__global__ void scan2_kernel(int* __restrict__ btot, int nb) {
  __shared__ int sh[128];
  int t = threadIdx.x;
  if (t < nb) sh[t] = btot[t];
  __syncthreads();
  if (t == 0) {
    int run = 0;
    for (int b = 0; b < nb; ++b) { int x = sh[b]; sh[b] = run; run += x; }
  }
  __syncthreads();
  if (t < nb) btot[t] = sh[t];
}

__global__ void scan3_kernel(const int* __restrict__ excl, const int* __restrict__ btot,
                             int* __restrict__ rowptr) {
  int i = blockIdx.x * TPB + threadIdx.x;
  if (i < NN) rowptr[i] = excl[i] + btot[i >> 10];
  if (i == NN) rowptr[NN] = NE;
}

// atomic-free fill: position = rowptr[c] + rank[e]
__global__ void fill2_kernel(const int* __restrict__ row, const int* __restrict__ col,
                             const float* __restrict__ w, const float* __restrict__ dis,
                             const int* __restrict__ rank, const int* __restrict__ rowptr,
                             int2* __restrict__ edges) {
  int e = blockIdx.x * TPB + threadIdx.x;
  if (e >= NE) return;
  int r = row[e], c = col[e];
  float nw = dis[r] * w[e] * dis[c];
  edges[rowptr[c] + rank[e]] = make_int2(r, __float_as_int(nw));
}

// W0 [384][128] f32 -> fragment-ordered bf16
__global__ void wfrag0_kernel(const float* __restrict__ W0, short* __restrict__ F) {
  int t = blockIdx.x * TPB + threadIdx.x;
  if (t >= 12 * 8 * 64) return;
  int l = t & 63, nt = (t >> 6) & 7, s = t >> 9;
  int c = nt * 16 + (l & 15);
  int kb = s * 32 + (l >> 4) * 8;
  short8v v;
#pragma unroll
  for (int j = 0; j < 8; ++j) v[j] = (short)f2bf(W0[(kb + j) * 128 + c]);
  *(short8v*)(F + (size_t)t * 8) = v;
}

// W1 [6][128][64] viewed as B[f][J]=W1[J>>6][f][J&63]
__global__ void wfrag1_kernel(const float* __restrict__ W1, short* __restrict__ F) {
  int t = blockIdx.x * TPB + threadIdx.x;
  if (t >= 4 * 24 * 64) return;
  int l = t & 63, nt = (t >> 6) % 24, s = t / (64 * 24);
  int J = nt * 16 + (l & 15);
  int fb = s * 32 + (l >> 4) * 8;
  const float* Wb = W1 + (size_t)(J >> 6) * (128 * 64) + (J & 63);
  short8v v;
#pragma unroll
  for (int j = 0; j < 8; ++j) v[j] = (short)f2bf(Wb[(size_t)(fb + j) * 64]);
  *(short8v*)(F + (size_t)t * 8) = v;
}

// x f32 [N][64] -> Hcat slice 0
__global__ void convx_kernel(const float* __restrict__ x, unsigned* __restrict__ hcat) {
  unsigned idx = blockIdx.x * (unsigned)TPB + threadIdx.x;
  if (idx >= (unsigned)NN * 32u) return;
  unsigned n = idx >> 5, p = idx & 31u;
  float2 v = *(const float2*)(x + (size_t)n * 64 + p * 2);
  hcat[(size_t)n * 192 + p] = pack2(v.x, v.y);
}

// ---------- hop: 8 lanes/node, 16B (8 bf16) per lane, dwordx4 gathers ----------
__device__ __forceinline__ void fma8(float* a, uint4 p, float w) {
  a[0] = fmaf(bflo(p.x), w, a[0]); a[1] = fmaf(bfhi(p.x), w, a[1]);
  a[2] = fmaf(bflo(p.y), w, a[2]); a[3] = fmaf(bfhi(p.y), w, a[3]);
  a[4] = fmaf(bflo(p.z), w, a[4]); a[5] = fmaf(bfhi(p.z), w, a[5]);
  a[6] = fmaf(bflo(p.w), w, a[6]); a[7] = fmaf(bfhi(p.w), w, a[7]);
}

template <bool YADD, bool FINAL>
__global__ void hop_kernel(const unsigned short* __restrict__ src, int sstride,
                           const int2* __restrict__ edges, const int* __restrict__ rowptr,
                           const unsigned short* __restrict__ y,
                           unsigned short* __restrict__ dst, int dstride,
                           const float* __restrict__ bias, float* __restrict__ outf) {
  unsigned n = blockIdx.x * 32u + (threadIdx.x >> 3);  // 32 nodes/block, grid exact
  unsigned lane = threadIdx.x & 7u;
  unsigned f0 = lane * 8u;  // bf16 index within 64-feat row
  int e = rowptr[n], e1 = rowptr[n + 1];
  float a[8] = {};
  for (; e + 1 < e1; e += 2) {
    int2 d0 = edges[e], d1 = edges[e + 1];
    uint4 p0 = *(const uint4*)(src + (size_t)(unsigned)d0.x * sstride + f0);
    uint4 p1 = *(const uint4*)(src + (size_t)(unsigned)d1.x * sstride + f0);
    fma8(a, p0, __int_as_float(d0.y));
    fma8(a, p1, __int_as_float(d1.y));
  }
  if (e < e1) {
    int2 d0 = edges[e];
    uint4 p0 = *(const uint4*)(src + (size_t)(unsigned)d0.x * sstride + f0);
    fma8(a, p0, __int_as_float(d0.y));
  }
  if (YADD) {
    uint4 yv = *(const uint4*)(y + (size_t)n * 384 + f0);
    a[0] += bflo(yv.x); a[1] += bfhi(yv.x);
    a[2] += bflo(yv.y); a[3] += bfhi(yv.y);
    a[4] += bflo(yv.z); a[5] += bfhi(yv.z);
    a[6] += bflo(yv.w); a[7] += bfhi(yv.w);
  }
  if (FINAL) {
    const float4* bp = (const float4*)(bias + f0);
    float4 bv0 = bp[0], bv1 = bp[1];
    float4 o0, o1;
    o0.x = a[0] + bv0.x; o0.y = a[1] + bv0.y; o0.z = a[2] + bv0.z; o0.w = a[3] + bv0.w;
    o1.x = a[4] + bv1.x; o1.y = a[5] + bv1.y; o1.z = a[6] + bv1.z; o1.w = a[7] + bv1.w;
    o0.x = o0.x >= 0.f ? o0.x : 0.01f * o0.x; o0.y = o0.y >= 0.f ? o0.y : 0.01f * o0.y;
    o0.z = o0.z >= 0.f ? o0.z : 0.01f * o0.z; o0.w = o0.w >= 0.f ? o0.w : 0.01f * o0.w;
    o1.x = o1.x >= 0.f ? o1.x : 0.01f * o1.x; o1.y = o1.y >= 0.f ? o1.y : 0.01f * o1.y;
    o1.z = o1.z >= 0.f ? o1.z : 0.01f * o1.z; o1.w = o1.w >= 0.f ? o1.w : 0.01f * o1.w;
    float4* op = (float4*)(outf + (size_t)n * 64 + f0);
    op[0] = o0; op[1] = o1;
  } else {
    uint4 st;
    st.x = pack2(a[0], a[1]); st.y = pack2(a[2], a[3]);
    st.z = pack2(a[4], a[5]); st.w = pack2(a[6], a[7]);
    *(uint4*)(dst + (size_t)n * dstride + f0) = st;
  }
}

// ---------- MFMA GEMM layer 0: Hcat[N][384] @ W0frag -> bias+lrelu -> H1[N][128] ----------
__global__ void gemm_l0(const unsigned short* __restrict__ A, const short* __restrict__ W0f,
                        const float* __restrict__ bias, unsigned short* __restrict__ H1) {
  int wave = threadIdx.x >> 6, lane = threadIdx.x & 63;
  int lrow = lane & 15, lk = lane >> 4;
  unsigned r0 = blockIdx.x * 64u + (unsigned)wave * 16u;
  unsigned arow = r0 + (unsigned)lrow;
  if (arow >= NN) arow = NN - 1;
  const short8v* Ab = (const short8v*)(A + (size_t)arow * 384 + (unsigned)lk * 8);
  const short8v* Bb = (const short8v*)W0f + lane;
  float4v acc[8] = {};
#pragma unroll
  for (int s = 0; s < 12; ++s) {
    short8v a = Ab[s * 4];
#pragma unroll
    for (int nt = 0; nt < 8; ++nt) {
      short8v b = Bb[(s * 8 + nt) * 64];
      acc[nt] = __builtin_amdgcn_mfma_f32_16x16x32_bf16(a, b, acc[nt], 0, 0, 0);
    }
  }
#pragma unroll
  for (int nt = 0; nt < 8; ++nt) {
    int c = nt * 16 + lrow;
    float bv = bias[c];
#pragma unroll
    for (int r = 0; r < 4; ++r) {
      unsigned n = r0 + (unsigned)(lk * 4 + r);
      if (n < NN) {
        float v = acc[nt][r] + bv;
        v = v >= 0.f ? v : 0.01f * v;
        H1[(size_t)n * 128 + c] = (unsigned short)f2bf(v);
      }
    }
  }
}

// ---------- MFMA GEMM layer 1: H1[N][128] @ W1frag -> Y[N][384] ----------
__global__ void gemm_l1(const unsigned short* __restrict__ A, const short* __restrict__ W1f,
                        unsigned short* __restrict__ Y) {
  int wave = threadIdx.x >> 6, lane = threadIdx.x & 63;
  int lrow = lane & 15, lk = lane >> 4;
  unsigned r0 = blockIdx.x * 64u + (unsigned)wave * 16u;
  unsigned arow = r0 + (unsigned)lrow;
  if (arow >= NN) arow = NN - 1;
  const short8v* Ab = (const short8v*)(A + (size_t)arow * 128 + (unsigned)lk * 8);
  const short8v* Bb = (const short8v*)W1f + lane;
  float4v acc[24] = {};
#pragma unroll
  for (int s = 0; s < 4; ++s) {
    short8v a = Ab[s * 4];
#pragma unroll
    for (int nt = 0; nt < 24; ++nt) {
      short8v b = Bb[(s * 24 + nt) * 64];
      acc[nt] = __builtin_amdgcn_mfma_f32_16x16x32_bf16(a, b, acc[nt], 0, 0, 0);
    }
  }
#pragma unroll
  for (int nt = 0; nt < 24; ++nt) {
    int c = nt * 16 + lrow;
#pragma unroll
    for (int r = 0; r < 4; ++r) {
      unsigned n = r0 + (unsigned)(lk * 4 + r);
      if (n < NN) Y[(size_t)n * 384 + c] = (unsigned short)f2bf(acc[nt][r]);
    }
  }
}

}  // namespace

extern "C" void kernel_launch(void* const* d_in, const int* in_sizes, int n_in,
                              void* d_out, int out_size, void* d_ws, size_t ws_size,
                              hipStream_t stream) {
  const float* x  = (const float*)d_in[0];
  const int*   ei = (const int*)d_in[1];
  const float* ew = (const float*)d_in[2];
  const float* W0 = (const float*)d_in[3];
  const float* b0 = (const float*)d_in[4];
  const float* W1 = (const float*)d_in[5];
  const float* b1 = (const float*)d_in[6];
  float* out = (float*)d_out;
  const int* row = ei;
  const int* col = ei + NE;

  // ws (4B words): dis[100352] | rowptr[100352] | btot[128] | edges int2[NE] | Hcat | H1
  constexpr size_t OFF_DIS    = 0;
  constexpr size_t OFF_ROWPTR = 100352;
  constexpr size_t OFF_BTOT   = OFF_ROWPTR + 100352;
  constexpr size_t OFF_EDGES  = OFF_BTOT + 128;
  constexpr size_t OFF_HCAT   = OFF_EDGES + 2 * (size_t)NE;
  constexpr size_t OFF_H1     = OFF_HCAT + (size_t)NN * 384 / 2;
  constexpr size_t WS_WORDS   = OFF_H1 + (size_t)NN * 128 / 2;
  if (ws_size < WS_WORDS * sizeof(float)) return;

  float* ws = (float*)d_ws;
  float* dis    = ws + OFF_DIS;
  int*   rowptr = (int*)(ws + OFF_ROWPTR);
  int*   btot   = (int*)(ws + OFF_BTOT);
  int2*  edges  = (int2*)(ws + OFF_EDGES);
  unsigned short* Hcat = (unsigned short*)(ws + OFF_HCAT);
  unsigned short* H1   = (unsigned short*)(ws + OFF_H1);
  // W fragments overlay dis region (dead after fill2): 2*24576 <= 100352
  short* W0f = (short*)(ws + OFF_DIS);
  short* W1f = (short*)(ws + OFF_DIS + 24576);
  // preprocessing transients: acc64+excl in H1 region, rank in Hcat region (both dead later)
  unsigned long long* acc64 = (unsigned long long*)(ws + OFF_H1);        // 200K words
  int* excl = (int*)(ws + OFF_H1 + 200704);
  int* rank = (int*)Hcat;                                                // 1.6M words
  // layer-1 Horner ping-pong overlays H1 region after gemm_l1 consumed it
  unsigned short* z0 = H1;
  unsigned short* z1 = H1 + (size_t)NN * 64;

  hipMemsetAsync(acc64, 0, NN * sizeof(unsigned long long), stream);
  pass1_kernel<<<(NE + TPB - 1) / TPB, TPB, 0, stream>>>(col, ew, acc64, rank);
  dis_kernel<<<(NN + TPB - 1) / TPB, TPB, 0, stream>>>(acc64, dis);
  scan1_kernel<<<98, 1024, 0, stream>>>(acc64, excl, btot);
  scan2_kernel<<<1, 128, 0, stream>>>(btot, 98);
  scan3_kernel<<<(NN + TPB) / TPB, TPB, 0, stream>>>(excl, btot, rowptr);
  fill2_kernel<<<(NE + TPB - 1) / TPB, TPB, 0, stream>>>(row, col, ew, dis, rank, rowptr, edges);
  // dis & scratch dead -> W fragments
  wfrag0_kernel<<<24, TPB, 0, stream>>>(W0, W0f);
  wfrag1_kernel<<<24, TPB, 0, stream>>>(W1, W1f);

  // layer 0
  convx_kernel<<<NN * 32 / TPB, TPB, 0, stream>>>(x, (unsigned*)Hcat);
  for (int k = 1; k <= 5; ++k) {
    hop_kernel<false, false><<<NN / 32, TPB, 0, stream>>>(
        Hcat + (k - 1) * 64, 384, edges, rowptr, nullptr,
        Hcat + k * 64, 384, nullptr, nullptr);
  }
  gemm_l0<<<(NN + 63) / 64, TPB, 0, stream>>>(Hcat, W0f, b0, H1);

  // layer 1: Y then Horner
  gemm_l1<<<(NN + 63) / 64, TPB, 0, stream>>>(H1, W1f, Hcat);
  const unsigned short* Y = Hcat;
  hop_kernel<true, false><<<NN / 32, TPB, 0, stream>>>(
      Y + 5 * 64, 384, edges, rowptr, Y + 4 * 64, z0, 64, nullptr, nullptr);
  hop_kernel<true, false><<<NN / 32, TPB, 0, stream>>>(
      z0, 64, edges, rowptr, Y + 3 * 64, z1, 64, nullptr, nullptr);
  hop_kernel<true, false><<<NN / 32, TPB, 0, stream>>>(
      z1, 64, edges, rowptr, Y + 2 * 64, z0, 64, nullptr, nullptr);
  hop_kernel<true, false><<<NN / 32, TPB, 0, stream>>>(
      z0, 64, edges, rowptr, Y + 1 * 64, z1, 64, nullptr, nullptr);
  hop_kernel<true, true><<<NN / 32, TPB, 0, stream>>>(
      z1, 64, edges, rowptr, Y + 0 * 64, nullptr, 0, b1, out);
}

// Round 6
// 620.830 us; speedup vs baseline: 10.5495x; 1.0580x over previous
//
#include <hip/hip_runtime.h>

// TAGConv x2 on MI355X — round 5: gemm_l1 col-split (occupancy 34->62%), 4x-unrolled
// gather hops, 2-edge/thread pass1. Storage bf16, accumulation f32.

namespace {
constexpr int NN = 100000;
constexpr int NE = 1600000;
constexpr int TPB = 256;

typedef __attribute__((ext_vector_type(8))) short short8v;
typedef __attribute__((ext_vector_type(4))) float float4v;

__device__ __forceinline__ float bflo(unsigned p) { return __uint_as_float(p << 16); }
__device__ __forceinline__ float bfhi(unsigned p) { return __uint_as_float(p & 0xffff0000u); }
__device__ __forceinline__ unsigned f2bf(float x) {
  unsigned u = __float_as_uint(x);
  return (u + 0x7fffu + ((u >> 16) & 1u)) >> 16;  // RNE
}
__device__ __forceinline__ unsigned pack2(float lo, float hi) {
  return f2bf(lo) | (f2bf(hi) << 16);
}

// ---------- preprocessing ----------
// One u64 atomic per edge: acc64[c] += (1<<40) | fixed24(w); old>>40 = rank, low40 = deg.
// 2 edges per thread for atomic MLP.
__global__ void pass1_kernel(const int* __restrict__ col, const float* __restrict__ w,
                             unsigned long long* __restrict__ acc64, int* __restrict__ rank) {
  int e0 = blockIdx.x * (TPB * 2) + threadIdx.x;
  int e1 = e0 + TPB;
  int c0 = col[e0], c1 = col[e1];
  unsigned long long v0 = (1ULL << 40) | (unsigned long long)__float2uint_rn(w[e0] * 16777216.0f);
  unsigned long long v1 = (1ULL << 40) | (unsigned long long)__float2uint_rn(w[e1] * 16777216.0f);
  unsigned long long o0 = atomicAdd(&acc64[c0], v0);
  unsigned long long o1 = atomicAdd(&acc64[c1], v1);
  rank[e0] = (int)(o0 >> 40);
  rank[e1] = (int)(o1 >> 40);
}

__global__ void dis_kernel(const unsigned long long* __restrict__ acc64,
                           float* __restrict__ dis) {
  int n = blockIdx.x * TPB + threadIdx.x;
  if (n >= NN) return;
  unsigned long long u = acc64[n] & ((1ULL << 40) - 1);
  float d = (float)u * (1.0f / 16777216.0f);
  dis[n] = d > 0.f ? rsqrtf(d) : 0.f;
}

__global__ void scan1_kernel(const unsigned long long* __restrict__ acc64,
                             int* __restrict__ excl, int* __restrict__ btot) {
  __shared__ int sh[1024];
  int i = blockIdx.x * 1024 + threadIdx.x;
  int v = (i < NN) ? (int)(acc64[i] >> 40) : 0;
  sh[threadIdx.x] = v;
  __syncthreads();
  for (int ofs = 1; ofs < 1024; ofs <<= 1) {
    int t = (threadIdx.x >= ofs) ? sh[threadIdx.x - ofs] : 0;
    __syncthreads();
    sh[threadIdx.x] += t;
    __syncthreads();
  }
  if (i < NN) excl[i] = sh[threadIdx.x] - v;
  if (threadIdx.x == 1023) btot[blockIdx.x] = sh[1023];
}

__global__ void scan2_kernel(int* __restrict__ btot, int nb) {
  __shared__ int sh[128];
  int t = threadIdx.x;
  if (t < nb) sh[t] = btot[t];
  __syncthreads();
  if (t == 0) {
    int run = 0;
    for (int b = 0; b < nb; ++b) { int x = sh[b]; sh[b] = run; run += x; }
  }
  __syncthreads();
  if (t < nb) btot[t] = sh[t];
}

__global__ void scan3_kernel(const int* __restrict__ excl, const int* __restrict__ btot,
                             int* __restrict__ rowptr) {
  int i = blockIdx.x * TPB + threadIdx.x;
  if (i < NN) rowptr[i] = excl[i] + btot[i >> 10];
  if (i == NN) rowptr[NN] = NE;
}

__global__ void fill2_kernel(const int* __restrict__ row, const int* __restrict__ col,
                             const float* __restrict__ w, const float* __restrict__ dis,
                             const int* __restrict__ rank, const int* __restrict__ rowptr,
                             int2* __restrict__ edges) {
  int e = blockIdx.x * TPB + threadIdx.x;
  if (e >= NE) return;
  int r = row[e], c = col[e];
  float nw = dis[r] * w[e] * dis[c];
  edges[rowptr[c] + rank[e]] = make_int2(r, __float_as_int(nw));
}

// W0 [384][128] f32 -> fragment-ordered bf16
__global__ void wfrag0_kernel(const float* __restrict__ W0, short* __restrict__ F) {
  int t = blockIdx.x * TPB + threadIdx.x;
  if (t >= 12 * 8 * 64) return;
  int l = t & 63, nt = (t >> 6) & 7, s = t >> 9;
  int c = nt * 16 + (l & 15);
  int kb = s * 32 + (l >> 4) * 8;
  short8v v;
#pragma unroll
  for (int j = 0; j < 8; ++j) v[j] = (short)f2bf(W0[(kb + j) * 128 + c]);
  *(short8v*)(F + (size_t)t * 8) = v;
}

// W1 [6][128][64] viewed as B[f][J]=W1[J>>6][f][J&63]
__global__ void wfrag1_kernel(const float* __restrict__ W1, short* __restrict__ F) {
  int t = blockIdx.x * TPB + threadIdx.x;
  if (t >= 4 * 24 * 64) return;
  int l = t & 63, nt = (t >> 6) % 24, s = t / (64 * 24);
  int J = nt * 16 + (l & 15);
  int fb = s * 32 + (l >> 4) * 8;
  const float* Wb = W1 + (size_t)(J >> 6) * (128 * 64) + (J & 63);
  short8v v;
#pragma unroll
  for (int j = 0; j < 8; ++j) v[j] = (short)f2bf(Wb[(size_t)(fb + j) * 64]);
  *(short8v*)(F + (size_t)t * 8) = v;
}

// x f32 [N][64] -> Hcat slice 0
__global__ void convx_kernel(const float* __restrict__ x, unsigned* __restrict__ hcat) {
  unsigned idx = blockIdx.x * (unsigned)TPB + threadIdx.x;
  if (idx >= (unsigned)NN * 32u) return;
  unsigned n = idx >> 5, p = idx & 31u;
  float2 v = *(const float2*)(x + (size_t)n * 64 + p * 2);
  hcat[(size_t)n * 192 + p] = pack2(v.x, v.y);
}

// ---------- hop: 8 lanes/node, 16B per lane, 4-edge unrolled dwordx4 gathers ----------
__device__ __forceinline__ void fma8(float* a, uint4 p, float w) {
  a[0] = fmaf(bflo(p.x), w, a[0]); a[1] = fmaf(bfhi(p.x), w, a[1]);
  a[2] = fmaf(bflo(p.y), w, a[2]); a[3] = fmaf(bfhi(p.y), w, a[3]);
  a[4] = fmaf(bflo(p.z), w, a[4]); a[5] = fmaf(bfhi(p.z), w, a[5]);
  a[6] = fmaf(bflo(p.w), w, a[6]); a[7] = fmaf(bfhi(p.w), w, a[7]);
}

template <bool YADD, bool FINAL>
__global__ void hop_kernel(const unsigned short* __restrict__ src, int sstride,
                           const int2* __restrict__ edges, const int* __restrict__ rowptr,
                           const unsigned short* __restrict__ y,
                           unsigned short* __restrict__ dst, int dstride,
                           const float* __restrict__ bias, float* __restrict__ outf) {
  unsigned n = blockIdx.x * 32u + (threadIdx.x >> 3);
  unsigned lane = threadIdx.x & 7u;
  unsigned f0 = lane * 8u;
  int e = rowptr[n], e1 = rowptr[n + 1];
  float a[8] = {};
  for (; e + 3 < e1; e += 4) {
    int2 d0 = edges[e], d1 = edges[e + 1], d2 = edges[e + 2], d3 = edges[e + 3];
    uint4 p0 = *(const uint4*)(src + (size_t)(unsigned)d0.x * sstride + f0);
    uint4 p1 = *(const uint4*)(src + (size_t)(unsigned)d1.x * sstride + f0);
    uint4 p2 = *(const uint4*)(src + (size_t)(unsigned)d2.x * sstride + f0);
    uint4 p3 = *(const uint4*)(src + (size_t)(unsigned)d3.x * sstride + f0);
    fma8(a, p0, __int_as_float(d0.y));
    fma8(a, p1, __int_as_float(d1.y));
    fma8(a, p2, __int_as_float(d2.y));
    fma8(a, p3, __int_as_float(d3.y));
  }
  if (e + 1 < e1) {
    int2 d0 = edges[e], d1 = edges[e + 1];
    uint4 p0 = *(const uint4*)(src + (size_t)(unsigned)d0.x * sstride + f0);
    uint4 p1 = *(const uint4*)(src + (size_t)(unsigned)d1.x * sstride + f0);
    fma8(a, p0, __int_as_float(d0.y));
    fma8(a, p1, __int_as_float(d1.y));
    e += 2;
  }
  if (e < e1) {
    int2 d0 = edges[e];
    uint4 p0 = *(const uint4*)(src + (size_t)(unsigned)d0.x * sstride + f0);
    fma8(a, p0, __int_as_float(d0.y));
  }
  if (YADD) {
    uint4 yv = *(const uint4*)(y + (size_t)n * 384 + f0);
    a[0] += bflo(yv.x); a[1] += bfhi(yv.x);
    a[2] += bflo(yv.y); a[3] += bfhi(yv.y);
    a[4] += bflo(yv.z); a[5] += bfhi(yv.z);
    a[6] += bflo(yv.w); a[7] += bfhi(yv.w);
  }
  if (FINAL) {
    const float4* bp = (const float4*)(bias + f0);
    float4 bv0 = bp[0], bv1 = bp[1];
    float4 o0, o1;
    o0.x = a[0] + bv0.x; o0.y = a[1] + bv0.y; o0.z = a[2] + bv0.z; o0.w = a[3] + bv0.w;
    o1.x = a[4] + bv1.x; o1.y = a[5] + bv1.y; o1.z = a[6] + bv1.z; o1.w = a[7] + bv1.w;
    o0.x = o0.x >= 0.f ? o0.x : 0.01f * o0.x; o0.y = o0.y >= 0.f ? o0.y : 0.01f * o0.y;
    o0.z = o0.z >= 0.f ? o0.z : 0.01f * o0.z; o0.w = o0.w >= 0.f ? o0.w : 0.01f * o0.w;
    o1.x = o1.x >= 0.f ? o1.x : 0.01f * o1.x; o1.y = o1.y >= 0.f ? o1.y : 0.01f * o1.y;
    o1.z = o1.z >= 0.f ? o1.z : 0.01f * o1.z; o1.w = o1.w >= 0.f ? o1.w : 0.01f * o1.w;
    float4* op = (float4*)(outf + (size_t)n * 64 + f0);
    op[0] = o0; op[1] = o1;
  } else {
    uint4 st;
    st.x = pack2(a[0], a[1]); st.y = pack2(a[2], a[3]);
    st.z = pack2(a[4], a[5]); st.w = pack2(a[6], a[7]);
    *(uint4*)(dst + (size_t)n * dstride + f0) = st;
  }
}

// ---------- MFMA GEMM layer 0: Hcat[N][384] @ W0frag -> bias+lrelu -> H1[N][128] ----------
__global__ void gemm_l0(const unsigned short* __restrict__ A, const short* __restrict__ W0f,
                        const float* __restrict__ bias, unsigned short* __restrict__ H1) {
  int wave = threadIdx.x >> 6, lane = threadIdx.x & 63;
  int lrow = lane & 15, lk = lane >> 4;
  unsigned r0 = blockIdx.x * 64u + (unsigned)wave * 16u;
  unsigned arow = r0 + (unsigned)lrow;
  if (arow >= NN) arow = NN - 1;
  const short8v* Ab = (const short8v*)(A + (size_t)arow * 384 + (unsigned)lk * 8);
  const short8v* Bb = (const short8v*)W0f + lane;
  float4v acc[8] = {};
#pragma unroll
  for (int s = 0; s < 12; ++s) {
    short8v a = Ab[s * 4];
#pragma unroll
    for (int nt = 0; nt < 8; ++nt) {
      short8v b = Bb[(s * 8 + nt) * 64];
      acc[nt] = __builtin_amdgcn_mfma_f32_16x16x32_bf16(a, b, acc[nt], 0, 0, 0);
    }
  }
#pragma unroll
  for (int nt = 0; nt < 8; ++nt) {
    int c = nt * 16 + lrow;
    float bv = bias[c];
#pragma unroll
    for (int r = 0; r < 4; ++r) {
      unsigned n = r0 + (unsigned)(lk * 4 + r);
      if (n < NN) {
        float v = acc[nt][r] + bv;
        v = v >= 0.f ? v : 0.01f * v;
        H1[(size_t)n * 128 + c] = (unsigned short)f2bf(v);
      }
    }
  }
}

// ---------- MFMA GEMM layer 1 (col-split): H1[N][128] @ W1frag -> Y[N][384], 8 tiles/block ----------
__global__ void gemm_l1(const unsigned short* __restrict__ A, const short* __restrict__ W1f,
                        unsigned short* __restrict__ Y) {
  int wave = threadIdx.x >> 6, lane = threadIdx.x & 63;
  int lrow = lane & 15, lk = lane >> 4;
  int yb = blockIdx.y * 8;  // col-tile base
  unsigned r0 = blockIdx.x * 64u + (unsigned)wave * 16u;
  unsigned arow = r0 + (unsigned)lrow;
  if (arow >= NN) arow = NN - 1;
  const short8v* Ab = (const short8v*)(A + (size_t)arow * 128 + (unsigned)lk * 8);
  const short8v* Bb = (const short8v*)W1f + lane;
  float4v acc[8] = {};
#pragma unroll
  for (int s = 0; s < 4; ++s) {
    short8v a = Ab[s * 4];
#pragma unroll
    for (int nt = 0; nt < 8; ++nt) {
      short8v b = Bb[(s * 24 + yb + nt) * 64];
      acc[nt] = __builtin_amdgcn_mfma_f32_16x16x32_bf16(a, b, acc[nt], 0, 0, 0);
    }
  }
#pragma unroll
  for (int nt = 0; nt < 8; ++nt) {
    int c = (yb + nt) * 16 + lrow;
#pragma unroll
    for (int r = 0; r < 4; ++r) {
      unsigned n = r0 + (unsigned)(lk * 4 + r);
      if (n < NN) Y[(size_t)n * 384 + c] = (unsigned short)f2bf(acc[nt][r]);
    }
  }
}

}  // namespace

extern "C" void kernel_launch(void* const* d_in, const int* in_sizes, int n_in,
                              void* d_out, int out_size, void* d_ws, size_t ws_size,
                              hipStream_t stream) {
  const float* x  = (const float*)d_in[0];
  const int*   ei = (const int*)d_in[1];
  const float* ew = (const float*)d_in[2];
  const float* W0 = (const float*)d_in[3];
  const float* b0 = (const float*)d_in[4];
  const float* W1 = (const float*)d_in[5];
  const float* b1 = (const float*)d_in[6];
  float* out = (float*)d_out;
  const int* row = ei;
  const int* col = ei + NE;

  constexpr size_t OFF_DIS    = 0;
  constexpr size_t OFF_ROWPTR = 100352;
  constexpr size_t OFF_BTOT   = OFF_ROWPTR + 100352;
  constexpr size_t OFF_EDGES  = OFF_BTOT + 128;
  constexpr size_t OFF_HCAT   = OFF_EDGES + 2 * (size_t)NE;
  constexpr size_t OFF_H1     = OFF_HCAT + (size_t)NN * 384 / 2;
  constexpr size_t WS_WORDS   = OFF_H1 + (size_t)NN * 128 / 2;
  if (ws_size < WS_WORDS * sizeof(float)) return;

  float* ws = (float*)d_ws;
  float* dis    = ws + OFF_DIS;
  int*   rowptr = (int*)(ws + OFF_ROWPTR);
  int*   btot   = (int*)(ws + OFF_BTOT);
  int2*  edges  = (int2*)(ws + OFF_EDGES);
  unsigned short* Hcat = (unsigned short*)(ws + OFF_HCAT);
  unsigned short* H1   = (unsigned short*)(ws + OFF_H1);
  short* W0f = (short*)(ws + OFF_DIS);
  short* W1f = (short*)(ws + OFF_DIS + 24576);
  unsigned long long* acc64 = (unsigned long long*)(ws + OFF_H1);
  int* excl = (int*)(ws + OFF_H1 + 200704);
  int* rank = (int*)Hcat;
  unsigned short* z0 = H1;
  unsigned short* z1 = H1 + (size_t)NN * 64;

  hipMemsetAsync(acc64, 0, NN * sizeof(unsigned long long), stream);
  pass1_kernel<<<NE / (TPB * 2), TPB, 0, stream>>>(col, ew, acc64, rank);
  dis_kernel<<<(NN + TPB - 1) / TPB, TPB, 0, stream>>>(acc64, dis);
  scan1_kernel<<<98, 1024, 0, stream>>>(acc64, excl, btot);
  scan2_kernel<<<1, 128, 0, stream>>>(btot, 98);
  scan3_kernel<<<(NN + TPB) / TPB, TPB, 0, stream>>>(excl, btot, rowptr);
  fill2_kernel<<<(NE + TPB - 1) / TPB, TPB, 0, stream>>>(row, col, ew, dis, rank, rowptr, edges);
  wfrag0_kernel<<<24, TPB, 0, stream>>>(W0, W0f);
  wfrag1_kernel<<<24, TPB, 0, stream>>>(W1, W1f);

  // layer 0
  convx_kernel<<<NN * 32 / TPB, TPB, 0, stream>>>(x, (unsigned*)Hcat);
  for (int k = 1; k <= 5; ++k) {
    hop_kernel<false, false><<<NN / 32, TPB, 0, stream>>>(
        Hcat + (k - 1) * 64, 384, edges, rowptr, nullptr,
        Hcat + k * 64, 384, nullptr, nullptr);
  }
  gemm_l0<<<(NN + 63) / 64, TPB, 0, stream>>>(Hcat, W0f, b0, H1);

  // layer 1: Y then Horner
  gemm_l1<<<dim3((NN + 63) / 64, 3), TPB, 0, stream>>>(H1, W1f, Hcat);
  const unsigned short* Y = Hcat;
  hop_kernel<true, false><<<NN / 32, TPB, 0, stream>>>(
      Y + 5 * 64, 384, edges, rowptr, Y + 4 * 64, z0, 64, nullptr, nullptr);
  hop_kernel<true, false><<<NN / 32, TPB, 0, stream>>>(
      z0, 64, edges, rowptr, Y + 3 * 64, z1, 64, nullptr, nullptr);
  hop_kernel<true, false><<<NN / 32, TPB, 0, stream>>>(
      z1, 64, edges, rowptr, Y + 2 * 64, z0, 64, nullptr, nullptr);
  hop_kernel<true, false><<<NN / 32, TPB, 0, stream>>>(
      z0, 64, edges, rowptr, Y + 1 * 64, z1, 64, nullptr, nullptr);
  hop_kernel<true, true><<<NN / 32, TPB, 0, stream>>>(
      z1, 64, edges, rowptr, Y + 0 * 64, nullptr, 0, b1, out);
}